// Round 2
// baseline (1042.411 us; speedup 1.0000x reference)
//
#include <hip/hip_runtime.h>
#include <stdint.h>

#define D_MODEL 512
#define NHEADS 8
#define DK 64
#define NB 8192
#define NTOK 14
#define ROWS (NB*NTOK)   // 114688

typedef unsigned short ushort_t;
typedef __attribute__((ext_vector_type(8))) short short8;
typedef __attribute__((ext_vector_type(4))) short short4v;
typedef __attribute__((ext_vector_type(4))) float f32x4;

__device__ __forceinline__ float bf2f(ushort_t u) {
    return __uint_as_float(((unsigned int)u) << 16);
}
__device__ __forceinline__ ushort_t f2bf(float f) {
    unsigned int u = __float_as_uint(f);
    unsigned int r = (u + 0x7FFFu + ((u >> 16) & 1u)) >> 16;
    return (ushort_t)r;
}

// fp32 -> bf16 conversion (rne), 4 elems/thread
__global__ void cvt_kernel(const float* __restrict__ src, ushort_t* __restrict__ dst, int n)
{
    int i = (blockIdx.x * blockDim.x + threadIdx.x) * 4;
    if (i + 3 < n) {
        float4 v = *(const float4*)(src + i);
        short4v o;
        o[0] = (short)f2bf(v.x);
        o[1] = (short)f2bf(v.y);
        o[2] = (short)f2bf(v.z);
        o[3] = (short)f2bf(v.w);
        *(short4v*)(dst + i) = o;
    }
}

// C[M x *] = A[M x 512] @ W^T + bias. A/W bf16, bias fp32, acc fp32.
// Output: bf16 to Cb if Cf==null, else fp32 to Cf.
// Col tile n0 = 128*blockIdx.y; weight selected by n0/512 (for fused QKV).
__global__ __launch_bounds__(256, 2) void gemm_bt(
    const ushort_t* __restrict__ A, int lda,
    const ushort_t* __restrict__ W0, const ushort_t* __restrict__ W1, const ushort_t* __restrict__ W2,
    const float* __restrict__ b0, const float* __restrict__ b1, const float* __restrict__ b2,
    ushort_t* __restrict__ Cb, float* __restrict__ Cf, int ldc)
{
    __shared__ __align__(16) ushort_t As[128 * 32];
    __shared__ __align__(16) ushort_t Bs[128 * 32];

    const int m0 = blockIdx.x * 128;
    const int n0 = blockIdx.y * 128;
    const int wsel = n0 >> 9;
    const ushort_t* W    = (wsel == 0) ? W0 : ((wsel == 1) ? W1 : W2);
    const float*    bias = (wsel == 0) ? b0 : ((wsel == 1) ? b1 : b2);
    const int nw = n0 & 511;

    const int tid  = threadIdx.x;
    const int lane = tid & 63;
    const int wave = tid >> 6;
    const int quad = lane >> 4;
    const int c    = lane & 15;
    const int wm   = (wave & 1) * 64;
    const int wn   = (wave >> 1) * 64;

    f32x4 acc[4][4];
    #pragma unroll
    for (int i = 0; i < 4; ++i)
        #pragma unroll
        for (int j = 0; j < 4; ++j)
            acc[i][j] = (f32x4){0.f, 0.f, 0.f, 0.f};

    for (int k0 = 0; k0 < 512; k0 += 32) {
        #pragma unroll
        for (int r = 0; r < 2; ++r) {
            int cidx = r * 256 + tid;        // 0..511, 4 x 16B chunks per row
            int row  = cidx >> 2;
            int kq   = (cidx & 3) * 8;
            *(short8*)&As[row * 32 + kq] =
                *(const short8*)(A + (size_t)(m0 + row) * lda + k0 + kq);
            *(short8*)&Bs[row * 32 + kq] =
                *(const short8*)(W + (size_t)(nw + row) * 512 + k0 + kq);
        }
        __syncthreads();

        short8 af[4], bfr[4];
        #pragma unroll
        for (int i = 0; i < 4; ++i) {
            af[i]  = *(const short8*)&As[(wm + i * 16 + c) * 32 + quad * 8];
            bfr[i] = *(const short8*)&Bs[(wn + i * 16 + c) * 32 + quad * 8];
        }
        #pragma unroll
        for (int i = 0; i < 4; ++i)
            #pragma unroll
            for (int j = 0; j < 4; ++j)
                acc[i][j] = __builtin_amdgcn_mfma_f32_16x16x32_bf16(af[i], bfr[j], acc[i][j], 0, 0, 0);
        __syncthreads();
    }

    // epilogue: C layout col=lane&15, row=quad*4+reg
    #pragma unroll
    for (int j = 0; j < 4; ++j) {
        int coln = wn + j * 16 + c;
        float bv = bias[nw + coln];
        int col  = n0 + coln;
        #pragma unroll
        for (int i = 0; i < 4; ++i) {
            #pragma unroll
            for (int r = 0; r < 4; ++r) {
                int row = m0 + wm + i * 16 + quad * 4 + r;
                float v = acc[i][j][r] + bv;
                if (Cf) Cf[(size_t)row * ldc + col] = v;
                else    Cb[(size_t)row * ldc + col] = f2bf(v);
            }
        }
    }
}

// One wave per (b, h). QKV: [ROWS][1536] bf16 (Q|K|V). O: [ROWS][512] bf16.
__global__ __launch_bounds__(256, 4) void attn_kernel(
    const ushort_t* __restrict__ QKV,
    const float* __restrict__ dist,
    const float* __restrict__ scale_p,
    const float* __restrict__ power_p,
    ushort_t* __restrict__ O)
{
    __shared__ __align__(16) ushort_t Pl[4][16 * 32];

    const int tid  = threadIdx.x;
    const int lane = tid & 63;
    const int wave = tid >> 6;
    const int id   = blockIdx.x * 4 + wave;   // b*8 + h
    const int b    = id >> 3;
    const int h    = id & 7;
    const int quad = lane >> 4;
    const int c    = lane & 15;

    const float scale = scale_p[0];
    const float power = power_p[0];

    const size_t rowbase = (size_t)b * NTOK;
    const int mrow = (c < NTOK) ? c : (NTOK - 1);

    // Q as A-operand (m = query = c, k = dk), K as B-operand (n = key = c, k = dk)
    const ushort_t* qp = QKV + (rowbase + mrow) * 1536 + h * 64 + quad * 8;
    short8 aq0 = *(const short8*)qp;
    short8 aq1 = *(const short8*)(qp + 32);
    const ushort_t* kp = QKV + (rowbase + mrow) * 1536 + 512 + h * 64 + quad * 8;
    short8 bk0 = *(const short8*)kp;
    short8 bk1 = *(const short8*)(kp + 32);

    f32x4 S = (f32x4){0.f, 0.f, 0.f, 0.f};
    S = __builtin_amdgcn_mfma_f32_16x16x32_bf16(aq0, bk0, S, 0, 0, 0);
    S = __builtin_amdgcn_mfma_f32_16x16x32_bf16(aq1, bk1, S, 0, 0, 0);

    // softmax over cols (key index) per row; C layout: col=c, row=quad*4+r
    float p4[4];
    #pragma unroll
    for (int r = 0; r < 4; ++r) {
        int row = quad * 4 + r;
        float s;
        if (c < NTOK && row < NTOK) {
            float d  = dist[row * NTOK + c];
            float dp = (d > 0.f) ? __expf(power * __logf(d)) : 0.f;
            float pri = scale / (1.f + dp);
            s = S[r] * 0.125f * pri;      // 1/sqrt(64)
        } else if (row >= NTOK) {
            s = 0.f;                       // garbage row, keep finite
        } else {
            s = -INFINITY;                 // col >= NTOK: excluded
        }
        float smax = s;
        #pragma unroll
        for (int off = 1; off < 16; off <<= 1)
            smax = fmaxf(smax, __shfl_xor(smax, off));
        float e = (c < NTOK) ? __expf(s - smax) : 0.f;
        float l = e;
        #pragma unroll
        for (int off = 1; off < 16; off <<= 1)
            l += __shfl_xor(l, off);
        p4[r] = e / l;
    }

    // P (C layout) -> LDS -> A-operand layout. Zero k=16..31 pad region.
    #pragma unroll
    for (int z = 0; z < 4; ++z) {
        int idx = lane * 4 + z;           // 0..255 over 16x16 pad region
        int zr = idx >> 4, zc = idx & 15;
        Pl[wave][zr * 32 + 16 + zc] = 0;
    }
    #pragma unroll
    for (int r = 0; r < 4; ++r)
        Pl[wave][(quad * 4 + r) * 32 + c] = f2bf(p4[r]);
    __syncthreads();

    short8 pf = *(const short8*)&Pl[wave][c * 32 + quad * 8];

    // V as B-operand per 16-col dk tile: n = dk = t*16+c, k = key = quad*8+j
    const ushort_t* Vb = QKV + rowbase * 1536 + 1024 + h * 64;
    f32x4 o[4];
    #pragma unroll
    for (int t = 0; t < 4; ++t) {
        short8 vf = (short8){0, 0, 0, 0, 0, 0, 0, 0};
        #pragma unroll
        for (int j = 0; j < 8; ++j) {
            int m = quad * 8 + j;
            if (m < NTOK)
                vf[j] = (short)Vb[(size_t)m * 1536 + t * 16 + c];
        }
        f32x4 z = (f32x4){0.f, 0.f, 0.f, 0.f};
        o[t] = __builtin_amdgcn_mfma_f32_16x16x32_bf16(pf, vf, z, 0, 0, 0);
    }

    #pragma unroll
    for (int r = 0; r < 4; ++r) {
        int row = quad * 4 + r;
        if (row < NTOK) {
            #pragma unroll
            for (int t = 0; t < 4; ++t)
                O[(rowbase + row) * 512 + h * 64 + t * 16 + c] = f2bf(o[t][r]);
        }
    }
}

extern "C" void kernel_launch(void* const* d_in, const int* in_sizes, int n_in,
                              void* d_out, int out_size, void* d_ws, size_t ws_size,
                              hipStream_t stream)
{
    const float* x     = (const float*)d_in[0];
    const float* Wq    = (const float*)d_in[1];
    const float* bq    = (const float*)d_in[2];
    const float* Wk    = (const float*)d_in[3];
    const float* bk    = (const float*)d_in[4];
    const float* Wv    = (const float*)d_in[5];
    const float* bv    = (const float*)d_in[6];
    const float* Wo    = (const float*)d_in[7];
    const float* bo    = (const float*)d_in[8];
    const float* scale = (const float*)d_in[9];
    const float* power = (const float*)d_in[10];
    const float* dist  = (const float*)d_in[11];

    float* out = (float*)d_out;

    // ws layout (bf16): [xb / att : ROWS*512][wb : 4*512*512][qkv : ROWS*1536]
    ushort_t* xb  = (ushort_t*)d_ws;                  // x bf16; reused as att
    ushort_t* wb  = xb + (size_t)ROWS * 512;
    ushort_t* qkv = wb + (size_t)4 * 512 * 512;

    dim3 blk(256);

    // fp32 -> bf16 converts
    const int NX = ROWS * 512;
    const int NW = 512 * 512;
    cvt_kernel<<<NX / 1024, blk, 0, stream>>>(x,  xb, NX);
    cvt_kernel<<<NW / 1024, blk, 0, stream>>>(Wq, wb + 0 * (size_t)NW, NW);
    cvt_kernel<<<NW / 1024, blk, 0, stream>>>(Wk, wb + 1 * (size_t)NW, NW);
    cvt_kernel<<<NW / 1024, blk, 0, stream>>>(Wv, wb + 2 * (size_t)NW, NW);
    cvt_kernel<<<NW / 1024, blk, 0, stream>>>(Wo, wb + 3 * (size_t)NW, NW);

    // Fused QKV projection: qkv[ROWS][1536] = x @ [Wq|Wk|Wv]^T + [bq|bk|bv]
    dim3 g1(ROWS / 128, 1536 / 128);
    gemm_bt<<<g1, blk, 0, stream>>>(xb, 512,
                                    wb, wb + (size_t)NW, wb + 2 * (size_t)NW,
                                    bq, bk, bv, qkv, nullptr, 1536);

    // Attention: one wave per (b,h); att overwrites xb (x no longer needed)
    dim3 g2((NB * NHEADS) / 4);
    attn_kernel<<<g2, blk, 0, stream>>>(qkv, dist, scale, power, xb);

    // Output projection (fp32 out): out = att @ Wo^T + bo
    dim3 g3(ROWS / 128, 512 / 128);
    gemm_bt<<<g3, blk, 0, stream>>>(xb, 512,
                                    wb + 3 * (size_t)NW, wb + 3 * (size_t)NW, wb + 3 * (size_t)NW,
                                    bo, bo, bo, nullptr, out, 512);
}

// Round 3
// 952.438 us; speedup vs baseline: 1.0945x; 1.0945x over previous
//
#include <hip/hip_runtime.h>
#include <stdint.h>

#define D_MODEL 512
#define NHEADS 8
#define DK 64
#define NB 8192
#define NTOK 14
#define ROWS (NB*NTOK)   // 114688

typedef unsigned short ushort_t;
typedef __attribute__((ext_vector_type(8))) short short8;
typedef __attribute__((ext_vector_type(4))) short short4v;
typedef __attribute__((ext_vector_type(4))) float f32x4;

__device__ __forceinline__ float bf2f(ushort_t u) {
    return __uint_as_float(((unsigned int)u) << 16);
}
__device__ __forceinline__ ushort_t f2bf(float f) {
    unsigned int u = __float_as_uint(f);
    unsigned int r = (u + 0x7FFFu + ((u >> 16) & 1u)) >> 16;
    return (ushort_t)r;
}

// async 16B global->LDS: lds dest must be wave-uniform base; HW deposits lane i at base + i*16B
__device__ __forceinline__ void async_copy16(const ushort_t* g, ushort_t* l) {
    __builtin_amdgcn_global_load_lds(
        (const __attribute__((address_space(1))) void*)g,
        (__attribute__((address_space(3))) void*)l,
        16, 0, 0);
}

// fp32 -> bf16 conversion (rne), 4 elems/thread
__global__ void cvt_kernel(const float* __restrict__ src, ushort_t* __restrict__ dst, int n)
{
    int i = (blockIdx.x * blockDim.x + threadIdx.x) * 4;
    if (i + 3 < n) {
        float4 v = *(const float4*)(src + i);
        short4v o;
        o[0] = (short)f2bf(v.x);
        o[1] = (short)f2bf(v.y);
        o[2] = (short)f2bf(v.z);
        o[3] = (short)f2bf(v.w);
        *(short4v*)(dst + i) = o;
    }
}

// C[M x *] = A[M x 512] @ W^T + bias. A/W bf16, bias fp32, acc fp32.
// Output: bf16 to Cb if Cf==null, else fp32 to Cf.
// blockIdx.x = col tile (fast-varying, for A-tile L2 reuse), blockIdx.y = row tile.
// Weight selected by n0/512 (for fused QKV).
__global__ __launch_bounds__(256, 2) void gemm_bt(
    const ushort_t* __restrict__ A, int lda,
    const ushort_t* __restrict__ W0, const ushort_t* __restrict__ W1, const ushort_t* __restrict__ W2,
    const float* __restrict__ b0, const float* __restrict__ b1, const float* __restrict__ b2,
    ushort_t* __restrict__ Cb, float* __restrict__ Cf, int ldc)
{
    __shared__ __align__(16) ushort_t As[128 * 32];
    __shared__ __align__(16) ushort_t Bs[128 * 32];
    __shared__ __align__(16) char Ep[4 * 32 * 72 * 4];  // per-wave epilogue staging

    const int m0 = blockIdx.y * 128;
    const int n0 = blockIdx.x * 128;
    const int wsel = n0 >> 9;
    const ushort_t* W    = (wsel == 0) ? W0 : ((wsel == 1) ? W1 : W2);
    const float*    bias = (wsel == 0) ? b0 : ((wsel == 1) ? b1 : b2);
    const int nw = n0 & 511;

    const int tid  = threadIdx.x;
    const int lane = tid & 63;
    const int wave = tid >> 6;
    const int quad = lane >> 4;
    const int c    = lane & 15;
    const int wm   = (wave & 1) * 64;
    const int wn   = (wave >> 1) * 64;

    f32x4 acc[4][4];
    #pragma unroll
    for (int i = 0; i < 4; ++i)
        #pragma unroll
        for (int j = 0; j < 4; ++j)
            acc[i][j] = (f32x4){0.f, 0.f, 0.f, 0.f};

    // chunk geometry: tile = 128 rows x 32 ushort = 512 chunks of 16B; chunk c
    // covers row c>>2, ushorts (c&3)*8.. and lands at LDS offset c*16B.
    for (int k0 = 0; k0 < 512; k0 += 32) {
        #pragma unroll
        for (int rnd = 0; rnd < 2; ++rnd) {
            int chunk = rnd * 256 + wave * 64 + lane;
            int row   = chunk >> 2;
            int kq    = (chunk & 3) * 8;
            int lbase = (rnd * 256 + wave * 64) * 8;   // wave-uniform ushort offset
            async_copy16(A + (size_t)(m0 + row) * lda + k0 + kq, &As[lbase]);
            async_copy16(W + (size_t)(nw + row) * 512 + k0 + kq, &Bs[lbase]);
        }
        __syncthreads();

        short8 af[4], bfr[4];
        #pragma unroll
        for (int i = 0; i < 4; ++i) {
            af[i]  = *(const short8*)&As[(wm + i * 16 + c) * 32 + quad * 8];
            bfr[i] = *(const short8*)&Bs[(wn + i * 16 + c) * 32 + quad * 8];
        }
        #pragma unroll
        for (int i = 0; i < 4; ++i)
            #pragma unroll
            for (int j = 0; j < 4; ++j)
                acc[i][j] = __builtin_amdgcn_mfma_f32_16x16x32_bf16(af[i], bfr[j], acc[i][j], 0, 0, 0);
        __syncthreads();
    }

    // Epilogue: per-wave LDS staging -> coalesced 16B stores.
    // acc C layout: col = wn + j*16 + c, row = wm + i*16 + quad*4 + r.
    if (Cf == nullptr) {
        // bf16 out: whole 64x64 wave tile, row stride 72 (pad kills bank conflicts)
        ushort_t* sl = (ushort_t*)Ep + wave * 64 * 72;
        #pragma unroll
        for (int i = 0; i < 4; ++i)
            #pragma unroll
            for (int j = 0; j < 4; ++j)
                #pragma unroll
                for (int r = 0; r < 4; ++r) {
                    int rl = i * 16 + quad * 4 + r;
                    int cl = j * 16 + c;
                    sl[rl * 72 + cl] = f2bf(acc[i][j][r] + bias[nw + wn + cl]);
                }
        #pragma unroll
        for (int t = 0; t < 8; ++t) {
            int rl = t * 8 + (lane >> 3);
            int cl = (lane & 7) * 8;
            short8 v = *(const short8*)&sl[rl * 72 + cl];
            *(short8*)&Cb[(size_t)(m0 + wm + rl) * ldc + n0 + wn + cl] = v;
        }
    } else {
        // fp32 out: two 32x64 half-tiles
        float* slf = (float*)Ep + wave * 32 * 72;
        #pragma unroll
        for (int half = 0; half < 2; ++half) {
            #pragma unroll
            for (int i2 = 0; i2 < 2; ++i2)
                #pragma unroll
                for (int j = 0; j < 4; ++j)
                    #pragma unroll
                    for (int r = 0; r < 4; ++r) {
                        int i  = half * 2 + i2;
                        int rl = i2 * 16 + quad * 4 + r;
                        int cl = j * 16 + c;
                        slf[rl * 72 + cl] = acc[i][j][r] + bias[nw + wn + cl];
                    }
            #pragma unroll
            for (int t = 0; t < 8; ++t) {
                int rl = t * 4 + (lane >> 4);
                int cl = (lane & 15) * 4;
                f32x4 v = *(const f32x4*)&slf[rl * 72 + cl];
                *(f32x4*)&Cf[(size_t)(m0 + wm + half * 32 + rl) * ldc + n0 + wn + cl] = v;
            }
        }
    }
}

// One wave per (b, h). QKV: [ROWS][1536] bf16 (Q|K|V). O: [ROWS][512] bf16.
__global__ __launch_bounds__(256, 4) void attn_kernel(
    const ushort_t* __restrict__ QKV,
    const float* __restrict__ dist,
    const float* __restrict__ scale_p,
    const float* __restrict__ power_p,
    ushort_t* __restrict__ O)
{
    __shared__ __align__(16) ushort_t Pl[4][16 * 32];

    const int tid  = threadIdx.x;
    const int lane = tid & 63;
    const int wave = tid >> 6;
    const int id   = blockIdx.x * 4 + wave;   // b*8 + h
    const int b    = id >> 3;
    const int h    = id & 7;
    const int quad = lane >> 4;
    const int c    = lane & 15;

    const float scale = scale_p[0];
    const float power = power_p[0];

    const size_t rowbase = (size_t)b * NTOK;
    const int mrow = (c < NTOK) ? c : (NTOK - 1);

    // Q as A-operand (m = query = c, k = dk), K as B-operand (n = key = c, k = dk)
    const ushort_t* qp = QKV + (rowbase + mrow) * 1536 + h * 64 + quad * 8;
    short8 aq0 = *(const short8*)qp;
    short8 aq1 = *(const short8*)(qp + 32);
    const ushort_t* kp = QKV + (rowbase + mrow) * 1536 + 512 + h * 64 + quad * 8;
    short8 bk0 = *(const short8*)kp;
    short8 bk1 = *(const short8*)(kp + 32);

    f32x4 S = (f32x4){0.f, 0.f, 0.f, 0.f};
    S = __builtin_amdgcn_mfma_f32_16x16x32_bf16(aq0, bk0, S, 0, 0, 0);
    S = __builtin_amdgcn_mfma_f32_16x16x32_bf16(aq1, bk1, S, 0, 0, 0);

    // softmax over cols (key index) per row; C layout: col=c, row=quad*4+r
    float p4[4];
    #pragma unroll
    for (int r = 0; r < 4; ++r) {
        int row = quad * 4 + r;
        float s;
        if (c < NTOK && row < NTOK) {
            float d  = dist[row * NTOK + c];
            float dp = (d > 0.f) ? __expf(power * __logf(d)) : 0.f;
            float pri = scale / (1.f + dp);
            s = S[r] * 0.125f * pri;      // 1/sqrt(64)
        } else if (row >= NTOK) {
            s = 0.f;                       // garbage row, keep finite
        } else {
            s = -INFINITY;                 // col >= NTOK: excluded
        }
        float smax = s;
        #pragma unroll
        for (int off = 1; off < 16; off <<= 1)
            smax = fmaxf(smax, __shfl_xor(smax, off));
        float e = (c < NTOK) ? __expf(s - smax) : 0.f;
        float l = e;
        #pragma unroll
        for (int off = 1; off < 16; off <<= 1)
            l += __shfl_xor(l, off);
        p4[r] = e / l;
    }

    // P (C layout) -> LDS -> A-operand layout. Zero k=16..31 pad region.
    #pragma unroll
    for (int z = 0; z < 4; ++z) {
        int idx = lane * 4 + z;           // 0..255 over 16x16 pad region
        int zr = idx >> 4, zc = idx & 15;
        Pl[wave][zr * 32 + 16 + zc] = 0;
    }
    #pragma unroll
    for (int r = 0; r < 4; ++r)
        Pl[wave][(quad * 4 + r) * 32 + c] = f2bf(p4[r]);
    __syncthreads();

    short8 pf = *(const short8*)&Pl[wave][c * 32 + quad * 8];

    // V as B-operand per 16-col dk tile: n = dk = t*16+c, k = key = quad*8+j
    const ushort_t* Vb = QKV + rowbase * 1536 + 1024 + h * 64;
    f32x4 o[4];
    #pragma unroll
    for (int t = 0; t < 4; ++t) {
        short8 vf = (short8){0, 0, 0, 0, 0, 0, 0, 0};
        #pragma unroll
        for (int j = 0; j < 8; ++j) {
            int m = quad * 8 + j;
            if (m < NTOK)
                vf[j] = (short)Vb[(size_t)m * 1536 + t * 16 + c];
        }
        f32x4 z = (f32x4){0.f, 0.f, 0.f, 0.f};
        o[t] = __builtin_amdgcn_mfma_f32_16x16x32_bf16(pf, vf, z, 0, 0, 0);
    }

    #pragma unroll
    for (int r = 0; r < 4; ++r) {
        int row = quad * 4 + r;
        if (row < NTOK) {
            #pragma unroll
            for (int t = 0; t < 4; ++t)
                O[(rowbase + row) * 512 + h * 64 + t * 16 + c] = f2bf(o[t][r]);
        }
    }
}

extern "C" void kernel_launch(void* const* d_in, const int* in_sizes, int n_in,
                              void* d_out, int out_size, void* d_ws, size_t ws_size,
                              hipStream_t stream)
{
    const float* x     = (const float*)d_in[0];
    const float* Wq    = (const float*)d_in[1];
    const float* bq    = (const float*)d_in[2];
    const float* Wk    = (const float*)d_in[3];
    const float* bk    = (const float*)d_in[4];
    const float* Wv    = (const float*)d_in[5];
    const float* bv    = (const float*)d_in[6];
    const float* Wo    = (const float*)d_in[7];
    const float* bo    = (const float*)d_in[8];
    const float* scale = (const float*)d_in[9];
    const float* power = (const float*)d_in[10];
    const float* dist  = (const float*)d_in[11];

    float* out = (float*)d_out;

    // ws layout (bf16): [xb / att : ROWS*512][wb : 4*512*512][qkv : ROWS*1536]
    ushort_t* xb  = (ushort_t*)d_ws;                  // x bf16; reused as att
    ushort_t* wb  = xb + (size_t)ROWS * 512;
    ushort_t* qkv = wb + (size_t)4 * 512 * 512;

    dim3 blk(256);

    // fp32 -> bf16 converts
    const int NX = ROWS * 512;
    const int NW = 512 * 512;
    cvt_kernel<<<NX / 1024, blk, 0, stream>>>(x,  xb, NX);
    cvt_kernel<<<NW / 1024, blk, 0, stream>>>(Wq, wb + 0 * (size_t)NW, NW);
    cvt_kernel<<<NW / 1024, blk, 0, stream>>>(Wk, wb + 1 * (size_t)NW, NW);
    cvt_kernel<<<NW / 1024, blk, 0, stream>>>(Wv, wb + 2 * (size_t)NW, NW);
    cvt_kernel<<<NW / 1024, blk, 0, stream>>>(Wo, wb + 3 * (size_t)NW, NW);

    // Fused QKV projection: qkv[ROWS][1536] = x @ [Wq|Wk|Wv]^T + [bq|bk|bv]
    // col tile fast-varying for A-tile L2/L3 reuse
    dim3 g1(1536 / 128, ROWS / 128);
    gemm_bt<<<g1, blk, 0, stream>>>(xb, 512,
                                    wb, wb + (size_t)NW, wb + 2 * (size_t)NW,
                                    bq, bk, bv, qkv, nullptr, 1536);

    // Attention: one wave per (b,h); att overwrites xb (x no longer needed)
    dim3 g2((NB * NHEADS) / 4);
    attn_kernel<<<g2, blk, 0, stream>>>(qkv, dist, scale, power, xb);

    // Output projection (fp32 out): out = att @ Wo^T + bo
    dim3 g3(512 / 128, ROWS / 128);
    gemm_bt<<<g3, blk, 0, stream>>>(xb, 512,
                                    wb + 3 * (size_t)NW, wb + 3 * (size_t)NW, wb + 3 * (size_t)NW,
                                    bo, bo, bo, nullptr, out, 512);
}